// Round 1
// baseline (586.264 us; speedup 1.0000x reference)
//
#include <hip/hip_runtime.h>
#include <hip/hip_bf16.h>

// HAttention1D: b=4, h=8, n=8192, d=64, bsz=16, 9 levels (0=fine .. 8=coarsest n=32)
// out[i] = sum_l y_l[i>>l] / (sum_l a_l[i>>l] + 1e-8)
// level 0: block-diagonal 16x16 attention; levels>=1: query block j vs sibling block j^1
// on mean-pooled q,k / sum-pooled v.
//
// ws layout: [k pyramid bf16 33.4MB][q pyramid bf16 33.4MB][v pyramid fp32 66.8MB]
// = 133,693,440 bytes total. Pyramid rows per bh: levels 1..8 = 4096+...+32 = 8160.

#define NBH 32
#define SEQN 8192
#define DIM 64
#define PYR_ROWS 8160

__constant__ int OFF_TAB[9] = {0, 0, 4096, 6144, 7168, 7680, 7936, 8064, 8128};

__device__ __forceinline__ void store_px(__hip_bfloat16* p, size_t idx, float x) {
    p[idx] = __float2bfloat16(x);
}
__device__ __forceinline__ void store_px(float* p, size_t idx, float x) {
    p[idx] = x;
}

// One 256-thread workgroup handles one (bh z, 256-row chunk). Thread (g=t>>6, d=t&63)
// loads 64 rows of column d, pools the pairwise tree in registers (levels 1..6),
// levels 7..8 combined via LDS.
template <bool IS_MEAN, typename OT>
__device__ __forceinline__ void pool_tensor(const float* __restrict__ in, OT* __restrict__ pyr,
                                            int z, int chunk, int g, int d,
                                            float (&lds)[4][64]) {
    const int rowbase = chunk * 256 + g * 64;
    const float sc = IS_MEAN ? 0.5f : 1.0f;
    float val[64];
    const float* src = in + ((size_t)z * SEQN + rowbase) * DIM + d;
#pragma unroll
    for (int r = 0; r < 64; ++r) val[r] = src[(size_t)r * DIM];

#pragma unroll
    for (int l = 1; l <= 6; ++l) {
        const int nr = 64 >> l;
#pragma unroll
        for (int r = 0; r < nr; ++r) val[r] = (val[2 * r] + val[2 * r + 1]) * sc;
        const size_t base = ((size_t)z * PYR_ROWS + OFF_TAB[l] + (rowbase >> l)) * DIM + d;
#pragma unroll
        for (int r = 0; r < nr; ++r) store_px(pyr, base + (size_t)r * DIM, val[r]);
    }
    // val[0] = level-6 row of this 64-row group
    lds[g][d] = val[0];
    __syncthreads();
    if (g == 0) {
        float l7a = (lds[0][d] + lds[1][d]) * sc;
        float l7b = (lds[2][d] + lds[3][d]) * sc;
        float l8 = (l7a + l7b) * sc;
        size_t b7 = ((size_t)z * PYR_ROWS + OFF_TAB[7] + chunk * 2) * DIM + d;
        store_px(pyr, b7, l7a);
        store_px(pyr, b7 + DIM, l7b);
        size_t b8 = ((size_t)z * PYR_ROWS + OFF_TAB[8] + chunk) * DIM + d;
        store_px(pyr, b8, l8);
    }
    __syncthreads();
}

__global__ __launch_bounds__(256) void pool_kernel(
    const float* __restrict__ q, const float* __restrict__ k, const float* __restrict__ v,
    __hip_bfloat16* __restrict__ qp, __hip_bfloat16* __restrict__ kp, float* __restrict__ vp) {
    const int chunk = blockIdx.x, z = blockIdx.y;
    const int t = threadIdx.x, d = t & 63, g = t >> 6;
    __shared__ float lds[4][64];
    pool_tensor<true>(q, qp, z, chunk, g, d, lds);
    pool_tensor<true>(k, kp, z, chunk, g, d, lds);
    pool_tensor<false>(v, vp, z, chunk, g, d, lds);
}

// One 64-thread wave per fine 16-row block B of bh z. Thread t: row i=t>>2, dim group
// g=t&3 (dims 16g..16g+15) -> output address t*16 within block: coalesced stores.
// LDS rows padded to stride 65 (tiles) / 17 (S) for bank-conflict-free access.
__global__ __launch_bounds__(64) void attend_kernel(
    const float* __restrict__ q, const float* __restrict__ k, const float* __restrict__ v,
    const __hip_bfloat16* __restrict__ qp, const __hip_bfloat16* __restrict__ kp,
    const float* __restrict__ vp, float* __restrict__ out) {
    const int B = blockIdx.x, z = blockIdx.y;
    const int t = threadIdx.x;
    const int i = t >> 2, g = t & 3;
    __shared__ float qs[16 * 65], ks[16 * 65], vs[16 * 65], Sb[16 * 17], asum[16];
    float Yacc[16];
#pragma unroll
    for (int dd = 0; dd < 16; ++dd) Yacc[dd] = 0.f;
    float Aacc = 0.f;
    const size_t zr = (size_t)z * SEQN;
    const size_t zp = (size_t)z * PYR_ROWS;

    for (int l = 0; l <= 8; ++l) {
        int c, qrow0, kb;
        if (l == 0) {
            c = 16; qrow0 = B * 16; kb = B;
        } else {
            c = (16 >> l); if (c < 1) c = 1;
            qrow0 = (B * 16) >> l;
            kb = (qrow0 >> 4) ^ 1;   // flipped sibling block
        }
        // ---- stage tiles into LDS ----
        if (l == 0) {
            const float* qsrc = q + (zr + (size_t)qrow0) * DIM;
            const float* ksrc = k + (zr + (size_t)kb * 16) * DIM;
            const float* vsrc = v + (zr + (size_t)kb * 16) * DIM;
            for (int m = t; m < 1024; m += 64) {
                int r = m >> 6, cc = m & 63;
                qs[r * 65 + cc] = qsrc[m];
                ks[r * 65 + cc] = ksrc[m];
                vs[r * 65 + cc] = vsrc[m];
            }
        } else {
            const __hip_bfloat16* qsrc = qp + (zp + OFF_TAB[l] + qrow0) * DIM;
            const __hip_bfloat16* ksrc = kp + (zp + OFF_TAB[l] + (size_t)kb * 16) * DIM;
            const float* vsrc = vp + (zp + OFF_TAB[l] + (size_t)kb * 16) * DIM;
            for (int m = t; m < c * 64; m += 64) {
                int r = m >> 6, cc = m & 63;
                qs[r * 65 + cc] = __bfloat162float(qsrc[m]);
            }
            for (int m = t; m < 1024; m += 64) {
                int r = m >> 6, cc = m & 63;
                ks[r * 65 + cc] = __bfloat162float(ksrc[m]);
                vs[r * 65 + cc] = vsrc[m];
            }
        }
        __syncthreads();
        // ---- S = (q_l . k_l^T) * d^-0.5 : c x 16 entries ----
        for (int e = t; e < c * 16; e += 64) {
            int pp = e >> 4, j = e & 15;
            float s = 0.f;
#pragma unroll
            for (int dd = 0; dd < 64; ++dd) s += qs[pp * 65 + dd] * ks[j * 65 + dd];
            Sb[pp * 17 + j] = s * 0.125f;
        }
        __syncthreads();
        // ---- per-row max, exp, rowsum (local softmax, unnormalized) ----
        if (t < c) {
            float mx = Sb[t * 17];
#pragma unroll
            for (int j = 1; j < 16; ++j) mx = fmaxf(mx, Sb[t * 17 + j]);
            float ssum = 0.f;
#pragma unroll
            for (int j = 0; j < 16; ++j) {
                float e2 = __expf(Sb[t * 17 + j] - mx);
                Sb[t * 17 + j] = e2;
                ssum += e2;
            }
            asum[t] = ssum;
        }
        __syncthreads();
        // ---- accumulate y_l[p(i)] into per-thread registers ----
        const int pl = (l == 0) ? i : (((B * 16 + i) >> l) - qrow0);
#pragma unroll
        for (int j = 0; j < 16; ++j) {
            float a = Sb[pl * 17 + j];
#pragma unroll
            for (int dd = 0; dd < 16; ++dd) Yacc[dd] += a * vs[j * 65 + g * 16 + dd];
        }
        Aacc += asum[pl];
        __syncthreads();
    }
    const float inv = 1.f / (Aacc + 1e-8f);
    float* obase = out + (zr + (size_t)B * 16) * DIM + t * 16;
#pragma unroll
    for (int dd = 0; dd < 16; ++dd) obase[dd] = Yacc[dd] * inv;
}

extern "C" void kernel_launch(void* const* d_in, const int* in_sizes, int n_in,
                              void* d_out, int out_size, void* d_ws, size_t ws_size,
                              hipStream_t stream) {
    const float* q = (const float*)d_in[0];
    const float* k = (const float*)d_in[1];
    const float* v = (const float*)d_in[2];
    float* out = (float*)d_out;

    // workspace carve (needs 133,693,440 B)
    char* w = (char*)d_ws;
    __hip_bfloat16* kp = (__hip_bfloat16*)w;                    // 33,423,360 B
    __hip_bfloat16* qp = (__hip_bfloat16*)(w + 33423360);       // 33,423,360 B
    float* vp = (float*)(w + 66846720);                         // 66,846,720 B

    pool_kernel<<<dim3(SEQN / 256, NBH), 256, 0, stream>>>(q, k, v, qp, kp, vp);
    attend_kernel<<<dim3(SEQN / 16, NBH), 64, 0, stream>>>(q, k, v, qp, kp, vp, out);
}

// Round 3
// 312.409 us; speedup vs baseline: 1.8766x; 1.8766x over previous
//
#include <hip/hip_runtime.h>

// HAttention1D: b=4,h=8,n=8192,d=64,bsz=16, levels 0..8.
// out[i] = sum_l y_l[i>>l] / (sum_l a_l[i>>l] + 1e-8); level 0: block-diagonal
// 16x16 attention; level l>=1: query block attends sibling block (B>>l)^1 on
// mean-pooled q,k (q pre-scaled d^-0.5) / sum-pooled v.
//
// R3 = safety rewrite: pool keeps the R1-proven structure (fp16 out, row-major);
// attend = 1 wave/block, typed-v8h LDS only (no punning), P/rowsum via
// ds_bpermute (no LDS round-trip), S via mfma_f32_16x16x32_f16,
// PV via mfma_f32_16x16x16f16 with u16-gathered B fragments.

#define NBH 32
#define SEQN 8192
#define DIM 64
#define PYR_ROWS 8160

typedef _Float16 v4h __attribute__((ext_vector_type(4)));
typedef _Float16 v8h __attribute__((ext_vector_type(8)));
typedef float v4f __attribute__((ext_vector_type(4)));
typedef _Float16 f16a __attribute__((may_alias));
typedef uint4 uint4a __attribute__((may_alias));

__constant__ int OFF_TAB[9] = {0, 0, 4096, 6144, 7168, 7680, 7936, 8064, 8128};

// ---------------- pool (R1-proven structure) ----------------
// MODE: 0=q (mean, *0.125), 1=k (mean), 2=v (sum). All row-major fp16.
template <int MODE>
__device__ __forceinline__ void pool_tensor(const float* __restrict__ in,
                                            _Float16* __restrict__ pyr,
                                            int z, int chunk, int g, int d,
                                            float (&lds)[4][64]) {
    const int rowbase = chunk * 256 + g * 64;
    const float sc = (MODE == 2) ? 1.0f : 0.5f;
    const size_t zb = (size_t)z * PYR_ROWS;
    float val[64];
    const float* src = in + ((size_t)z * SEQN + rowbase) * DIM + d;
#pragma unroll
    for (int r = 0; r < 64; ++r) val[r] = src[(size_t)r * DIM];
    if (MODE == 0) {
#pragma unroll
        for (int r = 0; r < 64; ++r) val[r] *= 0.125f;
    }
#pragma unroll
    for (int l = 1; l <= 6; ++l) {
        const int nr = 64 >> l;
#pragma unroll
        for (int r = 0; r < nr; ++r) val[r] = (val[2 * r] + val[2 * r + 1]) * sc;
        const size_t base = (zb + OFF_TAB[l] + (rowbase >> l)) * DIM + d;
#pragma unroll
        for (int r = 0; r < nr; ++r) pyr[base + (size_t)r * DIM] = (_Float16)val[r];
    }
    lds[g][d] = val[0];
    __syncthreads();
    if (g == 0) {
        float l7a = (lds[0][d] + lds[1][d]) * sc;
        float l7b = (lds[2][d] + lds[3][d]) * sc;
        float l8 = (l7a + l7b) * sc;
        size_t b7 = (zb + OFF_TAB[7] + chunk * 2) * DIM + d;
        pyr[b7] = (_Float16)l7a;
        pyr[b7 + DIM] = (_Float16)l7b;
        pyr[(zb + OFF_TAB[8] + chunk) * DIM + d] = (_Float16)l8;
    }
    __syncthreads();
}

__global__ __launch_bounds__(256) void pool_kernel(
    const float* __restrict__ q, const float* __restrict__ k, const float* __restrict__ v,
    _Float16* __restrict__ qp, _Float16* __restrict__ kp, _Float16* __restrict__ vp) {
    const int chunk = blockIdx.x, z = blockIdx.y;
    const int t = threadIdx.x, d = t & 63, g = t >> 6;
    __shared__ float lds[4][64];
    pool_tensor<0>(q, qp, z, chunk, g, d, lds);
    pool_tensor<1>(k, kp, z, chunk, g, d, lds);
    pool_tensor<2>(v, vp, z, chunk, g, d, lds);
}

// ---------------- attend ----------------
__device__ __forceinline__ float bperm(int lane, float x) {
    return __int_as_float(__builtin_amdgcn_ds_bpermute(lane << 2, __float_as_int(x)));
}

__global__ __launch_bounds__(64) void attend_kernel(
    const float* __restrict__ q, const float* __restrict__ k, const float* __restrict__ v,
    const _Float16* __restrict__ qp, const _Float16* __restrict__ kp,
    const _Float16* __restrict__ vp, float* __restrict__ out) {
    __shared__ v8h qsh[16][9];   // row-major, row = 8 data v8h + 1 pad
    __shared__ v8h ksh[16][9];
    __shared__ v8h vsh[16][9];
    const int t = threadIdx.x;
    const int m = t & 15, quad = t >> 4;
    const int B = blockIdx.x, z = blockIdx.y;
    const size_t zr = (size_t)z * SEQN * DIM;
    const size_t zp = (size_t)z * PYR_ROWS * DIM;

    v4f Y[4];
    float A[4];
#pragma unroll
    for (int nt = 0; nt < 4; ++nt) Y[nt] = (v4f){0.f, 0.f, 0.f, 0.f};
#pragma unroll
    for (int r = 0; r < 4; ++r) A[r] = 0.f;

    auto do_level = [&](int l) {
        // S^T[j][m] = sum_d K[j][d]*Qs[m][d]; A-frag rows = K, B-frag rows = Q.
        v4f s4 = {0.f, 0.f, 0.f, 0.f};
        s4 = __builtin_amdgcn_mfma_f32_16x16x32_f16(ksh[m][quad], qsh[m][quad], s4, 0, 0, 0);
        s4 = __builtin_amdgcn_mfma_f32_16x16x32_f16(ksh[m][4 + quad], qsh[m][4 + quad], s4, 0, 0, 0);
        // column (q-row m) softmax over 16 keys: 4 regs x 4 quads
        float mx = fmaxf(fmaxf(s4[0], s4[1]), fmaxf(s4[2], s4[3]));
        mx = fmaxf(mx, __shfl_xor(mx, 16, 64));
        mx = fmaxf(mx, __shfl_xor(mx, 32, 64));
        float e0 = __expf(s4[0] - mx), e1 = __expf(s4[1] - mx);
        float e2 = __expf(s4[2] - mx), e3 = __expf(s4[3] - mx);
        float sm = e0 + e1 + e2 + e3;
        sm += __shfl_xor(sm, 16, 64);
        sm += __shfl_xor(sm, 32, 64);
        // P A-frag: lane needs P[(m)>>l][quad*4+i] = e_i of lane ((m>>l) + 16*quad)
        const int sl = (m >> l) + (quad << 4);
        v4h pf;
        pf[0] = (_Float16)bperm(sl, e0);
        pf[1] = (_Float16)bperm(sl, e1);
        pf[2] = (_Float16)bperm(sl, e2);
        pf[3] = (_Float16)bperm(sl, e3);
        // PV: B-frag = V[quad*4+i][nt*16+m] gathered from row-major vsh
        const f16a* ve = (const f16a*)vsh;
#pragma unroll
        for (int nt = 0; nt < 4; ++nt) {
            const int dcol = nt * 16 + m;
            v4h vf;
#pragma unroll
            for (int i = 0; i < 4; ++i) vf[i] = ve[(quad * 4 + i) * 72 + dcol];
            Y[nt] = __builtin_amdgcn_mfma_f32_16x16x16f16(pf, vf, Y[nt], 0, 0, 0);
        }
        // rowsum: lane's rows quad*4+r need column-sum of column (quad*4+r)>>l
#pragma unroll
        for (int r = 0; r < 4; ++r) A[r] += bperm((quad * 4 + r) >> l, sm);
    };

    // ---- level 0: stage fine q,k,v (fp32->fp16, q*0.125) row-major ----
    {
        const float4* q4 = (const float4*)(q + zr + (size_t)B * 16 * DIM);
        const float4* k4 = (const float4*)(k + zr + (size_t)B * 16 * DIM);
        const float4* v4p = (const float4*)(v + zr + (size_t)B * 16 * DIM);
#pragma unroll
        for (int p = 0; p < 2; ++p) {
            const int idx = t + p * 64;       // 128 x 32B segments = 16 rows
            const int row = idx >> 3, c8 = idx & 7;
            float4 a0 = q4[2 * idx], a1 = q4[2 * idx + 1];
            v8h h;
            h[0] = (_Float16)(a0.x * 0.125f); h[1] = (_Float16)(a0.y * 0.125f);
            h[2] = (_Float16)(a0.z * 0.125f); h[3] = (_Float16)(a0.w * 0.125f);
            h[4] = (_Float16)(a1.x * 0.125f); h[5] = (_Float16)(a1.y * 0.125f);
            h[6] = (_Float16)(a1.z * 0.125f); h[7] = (_Float16)(a1.w * 0.125f);
            qsh[row][c8] = h;
            a0 = k4[2 * idx]; a1 = k4[2 * idx + 1];
            v8h hk;
            hk[0] = (_Float16)a0.x; hk[1] = (_Float16)a0.y;
            hk[2] = (_Float16)a0.z; hk[3] = (_Float16)a0.w;
            hk[4] = (_Float16)a1.x; hk[5] = (_Float16)a1.y;
            hk[6] = (_Float16)a1.z; hk[7] = (_Float16)a1.w;
            ksh[row][c8] = hk;
            a0 = v4p[2 * idx]; a1 = v4p[2 * idx + 1];
            v8h hv;
            hv[0] = (_Float16)a0.x; hv[1] = (_Float16)a0.y;
            hv[2] = (_Float16)a0.z; hv[3] = (_Float16)a0.w;
            hv[4] = (_Float16)a1.x; hv[5] = (_Float16)a1.y;
            hv[6] = (_Float16)a1.z; hv[7] = (_Float16)a1.w;
            vsh[row][c8] = hv;
        }
        do_level(0);
    }
    // ---- levels 1..8: stage from fp16 pyramids (row-major) ----
    for (int l = 1; l <= 8; ++l) {
        const int c = (l <= 4) ? (16 >> l) : 1;     // distinct coarse q rows
        const int qrow0 = (B * 16) >> l;
        const int kb = (B >> l) ^ 1;                // flipped sibling block
        const uint4a* qsrc = (const uint4a*)(qp + zp + (size_t)(OFF_TAB[l] + qrow0) * DIM);
        const uint4a* ksrc = (const uint4a*)(kp + zp + (size_t)(OFF_TAB[l] + kb * 16) * DIM);
        const uint4a* vsrc = (const uint4a*)(vp + zp + (size_t)(OFF_TAB[l] + kb * 16) * DIM);
        if (t < c * 8) {
            uint4 dq = qsrc[t];
            qsh[t >> 3][t & 7] = __builtin_bit_cast(v8h, dq);
        }
#pragma unroll
        for (int it = 0; it < 2; ++it) {
            const int cc = t + it * 64;
            uint4 dk = ksrc[cc];
            ksh[cc >> 3][cc & 7] = __builtin_bit_cast(v8h, dk);
            uint4 dv = vsrc[cc];
            vsh[cc >> 3][cc & 7] = __builtin_bit_cast(v8h, dv);
        }
        do_level(l);
    }
    // ---- epilogue: out = Y/(A+eps); D row = quad*4+r, col = nt*16+m ----
    float* ob = out + zr + (size_t)B * 16 * DIM;
#pragma unroll
    for (int r = 0; r < 4; ++r) {
        const float inv = 1.0f / (A[r] + 1e-8f);
#pragma unroll
        for (int nt = 0; nt < 4; ++nt)
            ob[(quad * 4 + r) * 64 + nt * 16 + m] = Y[nt][r] * inv;
    }
}

extern "C" void kernel_launch(void* const* d_in, const int* in_sizes, int n_in,
                              void* d_out, int out_size, void* d_ws, size_t ws_size,
                              hipStream_t stream) {
    const float* q = (const float*)d_in[0];
    const float* k = (const float*)d_in[1];
    const float* v = (const float*)d_in[2];
    float* out = (float*)d_out;

    // pyramids: 32 bh x 8160 rows x 64 dims fp16 = 33,423,360 B each (3x = 100.3 MB)
    const size_t PYR_BYTES = (size_t)NBH * PYR_ROWS * DIM * sizeof(_Float16);
    char* w = (char*)d_ws;
    _Float16* qp = (_Float16*)w;
    _Float16* kp = (_Float16*)(w + PYR_BYTES);
    _Float16* vp = (_Float16*)(w + 2 * PYR_BYTES);

    pool_kernel<<<dim3(SEQN / 256, NBH), 256, 0, stream>>>(q, k, v, qp, kp, vp);
    attend_kernel<<<dim3(SEQN / 16, NBH), 64, 0, stream>>>(q, k, v, qp, kp, vp, out);
}

// Round 4
// 308.983 us; speedup vs baseline: 1.8974x; 1.0111x over previous
//
#include <hip/hip_runtime.h>

// HAttention1D: b=4,h=8,n=8192,d=64,bsz=16, levels 0..8.
// out[i] = sum_l y_l[i>>l] / (sum_l a_l[i>>l] + 1e-8); level 0: block-diagonal
// 16x16 attention; level l>=1: query block attends sibling block (B>>l)^1 on
// mean-pooled q,k (q pre-scaled d^-0.5) / sum-pooled v.
//
// R4: pool also emits the FINE level as fp16 (q pre-scaled) when ws permits
// (FINE16 path) -> attend reads only fp16, staging = pure uint4 copies; attend
// pipelines levels (issue l+1 loads before computing l, fully unrolled).
// Fallback (!FINE16) = exact R3-proven path.

#define NBH 32
#define SEQN 8192
#define DIM 64
#define ROWS_F16 16352   // 8192+4096+...+32 (levels 0..8)
#define ROWS_CMP 8160    // 4096+...+32 (levels 1..8)

typedef _Float16 v4h __attribute__((ext_vector_type(4)));
typedef _Float16 v8h __attribute__((ext_vector_type(8)));
typedef float v4f __attribute__((ext_vector_type(4)));
typedef _Float16 f16a __attribute__((may_alias));
typedef uint4 uint4a __attribute__((may_alias));

__constant__ int OFF16[9] = {0, 8192, 12288, 14336, 15360, 15872, 16128, 16256, 16320};
__constant__ int OFF8[9]  = {0, 0, 4096, 6144, 7168, 7680, 7936, 8064, 8128};

// ---------------- pool ----------------
// MODE: 0=q (mean, *0.125), 1=k (mean), 2=v (sum). Row-major fp16.
template <int MODE, bool FINE16>
__device__ __forceinline__ void pool_tensor(const float* __restrict__ in,
                                            _Float16* __restrict__ pyr,
                                            int z, int chunk, int g, int d,
                                            float (&lds)[4][64]) {
    const int rowbase = chunk * 256 + g * 64;
    const float sc = (MODE == 2) ? 1.0f : 0.5f;
    const int ROWS = FINE16 ? ROWS_F16 : ROWS_CMP;
    const int* OFF = FINE16 ? OFF16 : OFF8;
    const size_t zb = (size_t)z * ROWS;
    float val[64];
    const float* src = in + ((size_t)z * SEQN + rowbase) * DIM + d;
#pragma unroll
    for (int r = 0; r < 64; ++r) val[r] = src[(size_t)r * DIM];
    if (MODE == 0) {
#pragma unroll
        for (int r = 0; r < 64; ++r) val[r] *= 0.125f;
    }
    if (FINE16) {
        const size_t b0 = (zb + OFF[0] + rowbase) * DIM + d;
#pragma unroll
        for (int r = 0; r < 64; ++r) pyr[b0 + (size_t)r * DIM] = (_Float16)val[r];
    }
#pragma unroll
    for (int l = 1; l <= 6; ++l) {
        const int nr = 64 >> l;
#pragma unroll
        for (int r = 0; r < nr; ++r) val[r] = (val[2 * r] + val[2 * r + 1]) * sc;
        const size_t base = (zb + OFF[l] + (rowbase >> l)) * DIM + d;
#pragma unroll
        for (int r = 0; r < nr; ++r) pyr[base + (size_t)r * DIM] = (_Float16)val[r];
    }
    lds[g][d] = val[0];
    __syncthreads();
    if (g == 0) {
        float l7a = (lds[0][d] + lds[1][d]) * sc;
        float l7b = (lds[2][d] + lds[3][d]) * sc;
        float l8 = (l7a + l7b) * sc;
        size_t b7 = (zb + OFF[7] + chunk * 2) * DIM + d;
        pyr[b7] = (_Float16)l7a;
        pyr[b7 + DIM] = (_Float16)l7b;
        pyr[(zb + OFF[8] + chunk) * DIM + d] = (_Float16)l8;
    }
    __syncthreads();
}

template <bool FINE16>
__global__ __launch_bounds__(256) void pool_kernel(
    const float* __restrict__ q, const float* __restrict__ k, const float* __restrict__ v,
    _Float16* __restrict__ qp, _Float16* __restrict__ kp, _Float16* __restrict__ vp) {
    const int chunk = blockIdx.x, z = blockIdx.y;
    const int t = threadIdx.x, d = t & 63, g = t >> 6;
    __shared__ float lds[4][64];
    pool_tensor<0, FINE16>(q, qp, z, chunk, g, d, lds);
    pool_tensor<1, FINE16>(k, kp, z, chunk, g, d, lds);
    pool_tensor<2, FINE16>(v, vp, z, chunk, g, d, lds);
}

// ---------------- attend ----------------
__device__ __forceinline__ float bperm(int lane, float x) {
    return __int_as_float(__builtin_amdgcn_ds_bpermute(lane << 2, __float_as_int(x)));
}

template <bool FINE16>
__global__ __launch_bounds__(64) void attend_kernel(
    const float* __restrict__ q, const float* __restrict__ k, const float* __restrict__ v,
    const _Float16* __restrict__ qp, const _Float16* __restrict__ kp,
    const _Float16* __restrict__ vp, float* __restrict__ out) {
    __shared__ v8h qsh[16][9];   // 8 data v8h + 1 pad per row
    __shared__ v8h ksh[16][9];
    __shared__ v8h vsh[16][9];
    const int t = threadIdx.x;
    const int m = t & 15, quad = t >> 4;
    const int B = blockIdx.x, z = blockIdx.y;
    const size_t zr = (size_t)z * SEQN * DIM;
    const size_t zp = (size_t)z * (FINE16 ? ROWS_F16 : ROWS_CMP) * DIM;

    v4f Y[4];
    float A[4];
#pragma unroll
    for (int nt = 0; nt < 4; ++nt) Y[nt] = (v4f){0.f, 0.f, 0.f, 0.f};
#pragma unroll
    for (int r = 0; r < 4; ++r) A[r] = 0.f;

    auto do_level = [&](int l) {
        // S^T[j][m] = sum_d K[j][d]*Qs[m][d]; A-frag rows = K, B-frag rows = Q.
        v4f s4 = {0.f, 0.f, 0.f, 0.f};
        s4 = __builtin_amdgcn_mfma_f32_16x16x32_f16(ksh[m][quad], qsh[m][quad], s4, 0, 0, 0);
        s4 = __builtin_amdgcn_mfma_f32_16x16x32_f16(ksh[m][4 + quad], qsh[m][4 + quad], s4, 0, 0, 0);
        float mx = fmaxf(fmaxf(s4[0], s4[1]), fmaxf(s4[2], s4[3]));
        mx = fmaxf(mx, __shfl_xor(mx, 16, 64));
        mx = fmaxf(mx, __shfl_xor(mx, 32, 64));
        float e0 = __expf(s4[0] - mx), e1 = __expf(s4[1] - mx);
        float e2 = __expf(s4[2] - mx), e3 = __expf(s4[3] - mx);
        float sm = e0 + e1 + e2 + e3;
        sm += __shfl_xor(sm, 16, 64);
        sm += __shfl_xor(sm, 32, 64);
        const int sl = (m >> l) + (quad << 4);
        v4h pf;
        pf[0] = (_Float16)bperm(sl, e0);
        pf[1] = (_Float16)bperm(sl, e1);
        pf[2] = (_Float16)bperm(sl, e2);
        pf[3] = (_Float16)bperm(sl, e3);
        const f16a* ve = (const f16a*)vsh;
#pragma unroll
        for (int nt = 0; nt < 4; ++nt) {
            const int dcol = nt * 16 + m;
            v4h vf;
#pragma unroll
            for (int i = 0; i < 4; ++i) vf[i] = ve[(quad * 4 + i) * 72 + dcol];
            Y[nt] = __builtin_amdgcn_mfma_f32_16x16x16f16(pf, vf, Y[nt], 0, 0, 0);
        }
#pragma unroll
        for (int r = 0; r < 4; ++r) A[r] += bperm((quad * 4 + r) >> l, sm);
    };

    if (FINE16) {
        // -------- unified pipelined path: all levels from fp16 pyramid --------
        auto issue_loads = [&](int l, uint4& nq0, uint4& nq1, uint4& nk0, uint4& nk1,
                               uint4& nv0, uint4& nv1) {
            const int c = (l == 0) ? 16 : ((l <= 4) ? (16 >> l) : 1);
            const int qrow0 = (B * 16) >> l;
            const int kb = (l == 0) ? B : ((B >> l) ^ 1);
            const uint4a* qsrc = (const uint4a*)(qp + zp + (size_t)(OFF16[l] + qrow0) * DIM);
            const uint4a* ksrc = (const uint4a*)(kp + zp + (size_t)(OFF16[l] + kb * 16) * DIM);
            const uint4a* vsrc = (const uint4a*)(vp + zp + (size_t)(OFF16[l] + kb * 16) * DIM);
            nk0 = ksrc[t]; nk1 = ksrc[t + 64];
            nv0 = vsrc[t]; nv1 = vsrc[t + 64];
            if (t < c * 8) nq0 = qsrc[t];
            if (l == 0) nq1 = qsrc[t + 64];
        };
        auto stage = [&](int l, uint4 q0, uint4 q1, uint4 k0, uint4 k1, uint4 v0, uint4 v1) {
            const int c = (l == 0) ? 16 : ((l <= 4) ? (16 >> l) : 1);
            const int row = t >> 3, c8 = t & 7;
            ksh[row][c8] = __builtin_bit_cast(v8h, k0);
            ksh[8 + row][c8] = __builtin_bit_cast(v8h, k1);
            vsh[row][c8] = __builtin_bit_cast(v8h, v0);
            vsh[8 + row][c8] = __builtin_bit_cast(v8h, v1);
            if (t < c * 8) qsh[row][c8] = __builtin_bit_cast(v8h, q0);
            if (l == 0) qsh[8 + row][c8] = __builtin_bit_cast(v8h, q1);
        };

        uint4 cq0{}, cq1{}, ck0{}, ck1{}, cv0{}, cv1{};
        issue_loads(0, cq0, cq1, ck0, ck1, cv0, cv1);
#pragma unroll
        for (int l = 0; l <= 8; ++l) {
            stage(l, cq0, cq1, ck0, ck1, cv0, cv1);
            uint4 nq0{}, nq1{}, nk0{}, nk1{}, nv0{}, nv1{};
            if (l < 8) issue_loads(l + 1, nq0, nq1, nk0, nk1, nv0, nv1);
            do_level(l);
            cq0 = nq0; cq1 = nq1; ck0 = nk0; ck1 = nk1; cv0 = nv0; cv1 = nv1;
        }
    } else {
        // -------- R3-proven fallback: fine fp32 staging + pyramid levels --------
        {
            const float4* q4 = (const float4*)(q + zr + (size_t)B * 16 * DIM);
            const float4* k4 = (const float4*)(k + zr + (size_t)B * 16 * DIM);
            const float4* v4p = (const float4*)(v + zr + (size_t)B * 16 * DIM);
#pragma unroll
            for (int p = 0; p < 2; ++p) {
                const int idx = t + p * 64;
                const int row = idx >> 3, c8 = idx & 7;
                float4 a0 = q4[2 * idx], a1 = q4[2 * idx + 1];
                v8h h;
                h[0] = (_Float16)(a0.x * 0.125f); h[1] = (_Float16)(a0.y * 0.125f);
                h[2] = (_Float16)(a0.z * 0.125f); h[3] = (_Float16)(a0.w * 0.125f);
                h[4] = (_Float16)(a1.x * 0.125f); h[5] = (_Float16)(a1.y * 0.125f);
                h[6] = (_Float16)(a1.z * 0.125f); h[7] = (_Float16)(a1.w * 0.125f);
                qsh[row][c8] = h;
                a0 = k4[2 * idx]; a1 = k4[2 * idx + 1];
                v8h hk;
                hk[0] = (_Float16)a0.x; hk[1] = (_Float16)a0.y;
                hk[2] = (_Float16)a0.z; hk[3] = (_Float16)a0.w;
                hk[4] = (_Float16)a1.x; hk[5] = (_Float16)a1.y;
                hk[6] = (_Float16)a1.z; hk[7] = (_Float16)a1.w;
                ksh[row][c8] = hk;
                a0 = v4p[2 * idx]; a1 = v4p[2 * idx + 1];
                v8h hv;
                hv[0] = (_Float16)a0.x; hv[1] = (_Float16)a0.y;
                hv[2] = (_Float16)a0.z; hv[3] = (_Float16)a0.w;
                hv[4] = (_Float16)a1.x; hv[5] = (_Float16)a1.y;
                hv[6] = (_Float16)a1.z; hv[7] = (_Float16)a1.w;
                vsh[row][c8] = hv;
            }
            do_level(0);
        }
        for (int l = 1; l <= 8; ++l) {
            const int c = (l <= 4) ? (16 >> l) : 1;
            const int qrow0 = (B * 16) >> l;
            const int kb = (B >> l) ^ 1;
            const uint4a* qsrc = (const uint4a*)(qp + zp + (size_t)(OFF8[l] + qrow0) * DIM);
            const uint4a* ksrc = (const uint4a*)(kp + zp + (size_t)(OFF8[l] + kb * 16) * DIM);
            const uint4a* vsrc = (const uint4a*)(vp + zp + (size_t)(OFF8[l] + kb * 16) * DIM);
            if (t < c * 8) {
                uint4 dq = qsrc[t];
                qsh[t >> 3][t & 7] = __builtin_bit_cast(v8h, dq);
            }
#pragma unroll
            for (int it = 0; it < 2; ++it) {
                const int cc = t + it * 64;
                uint4 dk = ksrc[cc];
                ksh[cc >> 3][cc & 7] = __builtin_bit_cast(v8h, dk);
                uint4 dv = vsrc[cc];
                vsh[cc >> 3][cc & 7] = __builtin_bit_cast(v8h, dv);
            }
            do_level(l);
        }
    }
    // ---- epilogue ----
    float* ob = out + zr + (size_t)B * 16 * DIM;
#pragma unroll
    for (int r = 0; r < 4; ++r) {
        const float inv = 1.0f / (A[r] + 1e-8f);
#pragma unroll
        for (int nt = 0; nt < 4; ++nt)
            ob[(quad * 4 + r) * 64 + nt * 16 + m] = Y[nt][r] * inv;
    }
}

extern "C" void kernel_launch(void* const* d_in, const int* in_sizes, int n_in,
                              void* d_out, int out_size, void* d_ws, size_t ws_size,
                              hipStream_t stream) {
    const float* q = (const float*)d_in[0];
    const float* k = (const float*)d_in[1];
    const float* v = (const float*)d_in[2];
    float* out = (float*)d_out;

    const size_t T16 = (size_t)NBH * ROWS_F16 * DIM * sizeof(_Float16);  // 66,977,792
    const size_t T8 = (size_t)NBH * ROWS_CMP * DIM * sizeof(_Float16);   // 33,423,360
    char* w = (char*)d_ws;

    if (ws_size >= 3 * T16) {
        _Float16* qp = (_Float16*)w;
        _Float16* kp = (_Float16*)(w + T16);
        _Float16* vp = (_Float16*)(w + 2 * T16);
        pool_kernel<true><<<dim3(SEQN / 256, NBH), 256, 0, stream>>>(q, k, v, qp, kp, vp);
        attend_kernel<true><<<dim3(SEQN / 16, NBH), 64, 0, stream>>>(q, k, v, qp, kp, vp, out);
    } else {
        _Float16* qp = (_Float16*)w;
        _Float16* kp = (_Float16*)(w + T8);
        _Float16* vp = (_Float16*)(w + 2 * T8);
        pool_kernel<false><<<dim3(SEQN / 256, NBH), 256, 0, stream>>>(q, k, v, qp, kp, vp);
        attend_kernel<false><<<dim3(SEQN / 16, NBH), 64, 0, stream>>>(q, k, v, qp, kp, vp, out);
    }
}